// Round 3
// baseline (10836.953 us; speedup 1.0000x reference)
//
#include <hip/hip_runtime.h>
#include <stdint.h>

#define B 4096
#define DX 100
#define H 512
#define DD 100
#define NSTEPS 64
#define ROWS 16

// ---------------- JAX threefry2x32 (20 rounds) ----------------
__device__ __forceinline__ void tf2x32(uint32_t k0, uint32_t k1,
                                       uint32_t x0, uint32_t x1,
                                       uint32_t& o0, uint32_t& o1)
{
  uint32_t ks2 = 0x1BD11BDAu ^ k0 ^ k1;
  x0 += k0; x1 += k1;
#define RND(r) { x0 += x1; x1 = (x1 << (r)) | (x1 >> (32 - (r))); x1 ^= x0; }
  RND(13) RND(15) RND(26) RND(6)   x0 += k1;  x1 += ks2 + 1u;
  RND(17) RND(29) RND(16) RND(24)  x0 += ks2; x1 += k0  + 2u;
  RND(13) RND(15) RND(26) RND(6)   x0 += k0;  x1 += k1  + 3u;
  RND(17) RND(29) RND(16) RND(24)  x0 += k1;  x1 += ks2 + 4u;
  RND(13) RND(15) RND(26) RND(6)   x0 += ks2; x1 += k0  + 5u;
#undef RND
  o0 = x0; o1 = x1;
}

// threefry_partitionable=True (JAX >= 0.4.30 default):
// split(key(42),64) -> foldlike: key[s] = threefry((0,42), (0, s)) -> (o0, o1)
__device__ __forceinline__ void step_keys(int step, uint32_t& k0, uint32_t& k1)
{
  tf2x32(0u, 42u, 0u, (uint32_t)step, k0, k1);
}

// random_bits 32-bit partitionable path: counter (0, m), bits = o0 ^ o1
__device__ __forceinline__ uint32_t jax_bits(uint32_t k0, uint32_t k1, uint32_t m)
{
  uint32_t a, b;
  tf2x32(k0, k1, 0u, m, a, b);
  return a ^ b;
}

// uniform(-1,1) -> sqrt(2)*erfinv(u), matching jax.random.normal f32 path
__device__ __forceinline__ float jax_normal_from_bits(uint32_t bits)
{
  float f = __uint_as_float((bits >> 9) | 0x3f800000u) - 1.0f;  // [0,1)
  const float lo = -0.99999994f;                                 // nextafter(-1,0)
  float u = fmaxf(lo, f * 2.0f + lo);   // (maxval-minval) rounds to exactly 2.0f
  float w = -log1pf(-u * u);
  float p;
  if (w < 5.0f) {
    w -= 2.5f;
    p =          2.81022636e-08f;
    p = fmaf(p, w, 3.43273939e-07f);
    p = fmaf(p, w, -3.5233877e-06f);
    p = fmaf(p, w, -4.39150654e-06f);
    p = fmaf(p, w, 0.00021858087f);
    p = fmaf(p, w, -0.00125372503f);
    p = fmaf(p, w, -0.00417768164f);
    p = fmaf(p, w, 0.246640727f);
    p = fmaf(p, w, 1.50140941f);
  } else {
    w = sqrtf(w) - 3.0f;
    p =          -0.000200214257f;
    p = fmaf(p, w, 0.000100950558f);
    p = fmaf(p, w, 0.00134934322f);
    p = fmaf(p, w, -0.00367342844f);
    p = fmaf(p, w, 0.00573950773f);
    p = fmaf(p, w, -0.0076224613f);
    p = fmaf(p, w, 0.00943887047f);
    p = fmaf(p, w, 1.00167406f);
    p = fmaf(p, w, 2.83297682f);
  }
  return 1.4142135623730951f * (p * u);
}

__device__ __forceinline__ float gelu(float v)
{
  return 0.5f * v * (1.0f + erff(v * 0.7071067811865475f));
}

// ---------------- init: x,y (in d_out), BN accumulators ----------------
__global__ void k_init(const float* __restrict__ y0, const float* __restrict__ x0,
                       float* __restrict__ x, float* __restrict__ y,
                       float* __restrict__ bn)
{
  int gid = blockIdx.x * blockDim.x + threadIdx.x;
  int stride = gridDim.x * blockDim.x;
  for (int i = gid; i < B * DX; i += stride) x[i] = x0[i % DX];
  for (int i = gid; i < B; i += stride) y[i] = y0[0];
  for (int i = gid; i < NSTEPS * 4 * H; i += stride) bn[i] = 0.0f;
}

// ---------------- step kernel 1: h1 = gelu([x,t]@W1+b1); g = gelu(h1@W2+b2); BN1 stats
__global__ __launch_bounds__(256) void k_l12(
    const float* __restrict__ x, const float* __restrict__ W1, const float* __restrict__ b1,
    const float* __restrict__ W2, const float* __restrict__ b2, float tval,
    float* __restrict__ g, float* __restrict__ bns, float* __restrict__ bnq)
{
  __shared__ float xt[ROWS][104];
  __shared__ float h1[ROWS][H];
  __shared__ float part[4][H];
  const int base = blockIdx.x * ROWS;
  const int tid = threadIdx.x;

  for (int idx = tid; idx < ROWS * 101; idx += 256) {
    int r = idx / 101, k = idx - r * 101;
    xt[r][k] = (k < DX) ? x[(base + r) * DX + k] : tval;
  }
  __syncthreads();

  const int tc = tid & 63, tr = tid >> 6;
  float acc[4][8];
#pragma unroll
  for (int i = 0; i < 4; i++)
#pragma unroll
    for (int j = 0; j < 8; j++) acc[i][j] = 0.0f;

  for (int k = 0; k < 101; k++) {
    float wv[8];
#pragma unroll
    for (int j = 0; j < 8; j++) wv[j] = W1[k * H + tc + 64 * j];
#pragma unroll
    for (int i = 0; i < 4; i++) {
      float a = xt[tr + 4 * i][k];
#pragma unroll
      for (int j = 0; j < 8; j++) acc[i][j] = fmaf(a, wv[j], acc[i][j]);
    }
  }
#pragma unroll
  for (int i = 0; i < 4; i++)
#pragma unroll
    for (int j = 0; j < 8; j++) {
      int c = tc + 64 * j;
      h1[tr + 4 * i][c] = gelu(acc[i][j] + b1[c]);
    }
  __syncthreads();

  // layer 2
#pragma unroll
  for (int i = 0; i < 4; i++)
#pragma unroll
    for (int j = 0; j < 8; j++) acc[i][j] = 0.0f;

  for (int k = 0; k < H; k++) {
    float wv[8];
#pragma unroll
    for (int j = 0; j < 8; j++) wv[j] = W2[k * H + tc + 64 * j];
#pragma unroll
    for (int i = 0; i < 4; i++) {
      float a = h1[tr + 4 * i][k];
#pragma unroll
      for (int j = 0; j < 8; j++) acc[i][j] = fmaf(a, wv[j], acc[i][j]);
    }
  }

  float qacc[8];
#pragma unroll
  for (int j = 0; j < 8; j++) {
    int c = tc + 64 * j;
    float bb = b2[c];
    float s = 0.0f, q = 0.0f;
#pragma unroll
    for (int i = 0; i < 4; i++) {
      float v = gelu(acc[i][j] + bb);
      g[(base + tr + 4 * i) * H + c] = v;
      s += v; q += v * v;
    }
    part[tr][c] = s;
    qacc[j] = q;
  }
  __syncthreads();
  for (int c = tid; c < H; c += 256)
    unsafeAtomicAdd(&bns[c], part[0][c] + part[1][c] + part[2][c] + part[3][c]);
  __syncthreads();
#pragma unroll
  for (int j = 0; j < 8; j++) part[tr][tc + 64 * j] = qacc[j];
  __syncthreads();
  for (int c = tid; c < H; c += 256)
    unsafeAtomicAdd(&bnq[c], part[0][c] + part[1][c] + part[2][c] + part[3][c]);
}

// ---------------- step kernel 2: n2 = BN1(g); g = gelu(n2@W3+b3); BN2 stats
__global__ __launch_bounds__(256) void k_bn_l3(
    float* g,  // in/out (row-local, safe)
    const float* __restrict__ bns, const float* __restrict__ bnq,
    const float* __restrict__ gamma, const float* __restrict__ beta,
    const float* __restrict__ W, const float* __restrict__ bvec,
    float* __restrict__ obns, float* __restrict__ obnq)
{
  __shared__ float sc[H], sh[H];
  __shared__ float nt[ROWS][H];
  __shared__ float part[4][H];
  const int base = blockIdx.x * ROWS;
  const int tid = threadIdx.x;

  for (int c = tid; c < H; c += 256) {
    float m = bns[c] * (1.0f / B);
    float v = bnq[c] * (1.0f / B) - m * m;
    float s = gamma[c] * rsqrtf(v + 1e-5f);
    sc[c] = s; sh[c] = beta[c] - m * s;
  }
  __syncthreads();
  for (int idx = tid; idx < ROWS * H; idx += 256) {
    int r = idx >> 9, c = idx & (H - 1);
    nt[r][c] = fmaf(g[(base + r) * H + c], sc[c], sh[c]);
  }
  __syncthreads();

  const int tc = tid & 63, tr = tid >> 6;
  float acc[4][8];
#pragma unroll
  for (int i = 0; i < 4; i++)
#pragma unroll
    for (int j = 0; j < 8; j++) acc[i][j] = 0.0f;

  for (int k = 0; k < H; k++) {
    float wv[8];
#pragma unroll
    for (int j = 0; j < 8; j++) wv[j] = W[k * H + tc + 64 * j];
#pragma unroll
    for (int i = 0; i < 4; i++) {
      float a = nt[tr + 4 * i][k];
#pragma unroll
      for (int j = 0; j < 8; j++) acc[i][j] = fmaf(a, wv[j], acc[i][j]);
    }
  }

  float qacc[8];
#pragma unroll
  for (int j = 0; j < 8; j++) {
    int c = tc + 64 * j;
    float bb = bvec[c];
    float s = 0.0f, q = 0.0f;
#pragma unroll
    for (int i = 0; i < 4; i++) {
      float v = gelu(acc[i][j] + bb);
      g[(base + tr + 4 * i) * H + c] = v;
      s += v; q += v * v;
    }
    part[tr][c] = s;
    qacc[j] = q;
  }
  __syncthreads();
  for (int c = tid; c < H; c += 256)
    unsafeAtomicAdd(&obns[c], part[0][c] + part[1][c] + part[2][c] + part[3][c]);
  __syncthreads();
#pragma unroll
  for (int j = 0; j < 8; j++) part[tr][tc + 64 * j] = qacc[j];
  __syncthreads();
  for (int c = tid; c < H; c += 256)
    unsafeAtomicAdd(&obnq[c], part[0][c] + part[1][c] + part[2][c] + part[3][c]);
}

// ---------------- step kernel 3: n3 = BN2(g); z = n3@W4+b4; RNG; update x,y
__global__ __launch_bounds__(256) void k_bn_l4(
    const float* __restrict__ g,
    const float* __restrict__ bns, const float* __restrict__ bnq,
    const float* __restrict__ gamma, const float* __restrict__ beta,
    const float* __restrict__ W4, const float* __restrict__ b4,
    int step, float* __restrict__ x, float* __restrict__ y)
{
  __shared__ float sc[H], sh[H];
  __shared__ float n3[ROWS][H];
  __shared__ float zzb[ROWS][DD + 4];
  __shared__ float zwb[ROWS][DD + 4];
  const int base = blockIdx.x * ROWS;
  const int tid = threadIdx.x;

  for (int c = tid; c < H; c += 256) {
    float m = bns[c] * (1.0f / B);
    float v = bnq[c] * (1.0f / B) - m * m;
    float s = gamma[c] * rsqrtf(v + 1e-5f);
    sc[c] = s; sh[c] = beta[c] - m * s;
  }
  __syncthreads();
  for (int idx = tid; idx < ROWS * H; idx += 256) {
    int r = idx >> 9, c = idx & (H - 1);
    n3[r][c] = fmaf(g[(base + r) * H + c], sc[c], sh[c]);
  }
  __syncthreads();

  const int tc = tid & 127, tr = tid >> 7;   // 2 row-groups, rows tr + 2*i
  float acc[8];
#pragma unroll
  for (int i = 0; i < 8; i++) acc[i] = 0.0f;

  if (tc < DD) {
    for (int k = 0; k < H; k++) {
      float w = W4[k * DD + tc];
#pragma unroll
      for (int i = 0; i < 8; i++) acc[i] = fmaf(n3[tr + 2 * i][k], w, acc[i]);
    }
    uint32_t k0, k1;
    step_keys(step, k0, k1);
    const float bb = b4[tc];
#pragma unroll
    for (int i = 0; i < 8; i++) {
      int r = tr + 2 * i;
      int grow = base + r;
      float z = acc[i] + bb;
      uint32_t m = (uint32_t)grow * (uint32_t)DD + (uint32_t)tc;
      float dW = 0.125f * jax_normal_from_bits(jax_bits(k0, k1, m));
      zzb[r][tc] = z * z;
      zwb[r][tc] = z * dW;
      x[grow * DX + tc] += 1.4142135623730951f * dW;
    }
  }
  __syncthreads();
  if (tid < ROWS) {
    float s1 = 0.0f, s2 = 0.0f;
    for (int d = 0; d < DD; d++) { s1 += zzb[tid][d]; s2 += zwb[tid][d]; }
    const float dt = 1.0f / NSTEPS;
    y[base + tid] += 0.5f * dt * s1 + s2;   // y - f*dt + z.dW, f = -0.5*||z||^2
  }
}

extern "C" void kernel_launch(void* const* d_in, const int* in_sizes, int n_in,
                              void* d_out, int out_size, void* d_ws, size_t ws_size,
                              hipStream_t stream)
{
  const float* y0  = (const float*)d_in[0];
  const float* W1  = (const float*)d_in[1];
  const float* b1  = (const float*)d_in[2];
  const float* W2  = (const float*)d_in[3];
  const float* b2  = (const float*)d_in[4];
  const float* W3  = (const float*)d_in[5];
  const float* b3  = (const float*)d_in[6];
  const float* W4  = (const float*)d_in[7];
  const float* b4  = (const float*)d_in[8];
  const float* ga1 = (const float*)d_in[9];
  const float* be1 = (const float*)d_in[10];
  const float* ga2 = (const float*)d_in[11];
  const float* be2 = (const float*)d_in[12];
  const float* x0  = (const float*)d_in[13];

  // x, y live directly in d_out
  float* x = (float*)d_out;        // B*DX
  float* y = x + B * DX;           // B

  // ws: bn stats first (small), then g
  float* ws = (float*)d_ws;
  float* bn = ws;                  // NSTEPS*4*H floats = 512 KB
  float* g  = bn + NSTEPS * 4 * H; // B*H floats = 8 MB

  k_init<<<512, 256, 0, stream>>>(y0, x0, x, y, bn);

  const float dt = 1.0f / NSTEPS;
  for (int s = 0; s < NSTEPS; ++s) {
    float* bn1s = bn + s * 4 * H;
    float* bn1q = bn1s + H;
    float* bn2s = bn1s + 2 * H;
    float* bn2q = bn1s + 3 * H;
    k_l12  <<<B / ROWS, 256, 0, stream>>>(x, W1, b1, W2, b2, (float)s * dt, g, bn1s, bn1q);
    k_bn_l3<<<B / ROWS, 256, 0, stream>>>(g, bn1s, bn1q, ga1, be1, W3, b3, bn2s, bn2q);
    k_bn_l4<<<B / ROWS, 256, 0, stream>>>(g, bn2s, bn2q, ga2, be2, W4, b4, s, x, y);
  }
}

// Round 4
// 5104.100 us; speedup vs baseline: 2.1232x; 2.1232x over previous
//
#include <hip/hip_runtime.h>
#include <stdint.h>

#define B 4096
#define DX 100
#define H 512
#define DD 100
#define NSTEPS 64
#define KIN 128      // padded input K for layer 1 (101 -> 128)
#define N4 112       // padded N for layer 4 (100 -> 112)

typedef short bf8 __attribute__((ext_vector_type(8)));    // 8 x bf16 (4 VGPR)
typedef float f32x4 __attribute__((ext_vector_type(4)));  // MFMA C/D

__device__ __forceinline__ ushort f2bf(float f) {
  uint32_t u = __float_as_uint(f);
  u += 0x7fffu + ((u >> 16) & 1u);   // RNE
  return (ushort)(u >> 16);
}
__device__ __forceinline__ float bf2f(ushort h) {
  return __uint_as_float((uint32_t)h << 16);
}
__device__ __forceinline__ f32x4 mfma16(bf8 a, bf8 b, f32x4 c) {
  return __builtin_amdgcn_mfma_f32_16x16x32_bf16(a, b, c, 0, 0, 0);
}

// ---------------- JAX threefry2x32 (20 rounds) ----------------
__device__ __forceinline__ void tf2x32(uint32_t k0, uint32_t k1,
                                       uint32_t x0, uint32_t x1,
                                       uint32_t& o0, uint32_t& o1)
{
  uint32_t ks2 = 0x1BD11BDAu ^ k0 ^ k1;
  x0 += k0; x1 += k1;
#define RND(r) { x0 += x1; x1 = (x1 << (r)) | (x1 >> (32 - (r))); x1 ^= x0; }
  RND(13) RND(15) RND(26) RND(6)   x0 += k1;  x1 += ks2 + 1u;
  RND(17) RND(29) RND(16) RND(24)  x0 += ks2; x1 += k0  + 2u;
  RND(13) RND(15) RND(26) RND(6)   x0 += k0;  x1 += k1  + 3u;
  RND(17) RND(29) RND(16) RND(24)  x0 += k1;  x1 += ks2 + 4u;
  RND(13) RND(15) RND(26) RND(6)   x0 += ks2; x1 += k0  + 5u;
#undef RND
  o0 = x0; o1 = x1;
}

// threefry_partitionable=True: split(key(42),64) -> key[s] = threefry((0,42),(0,s))
__device__ __forceinline__ void step_keys(int step, uint32_t& k0, uint32_t& k1)
{
  tf2x32(0u, 42u, 0u, (uint32_t)step, k0, k1);
}
// partitionable random_bits: counter (0,m), bits = o0 ^ o1
__device__ __forceinline__ uint32_t jax_bits(uint32_t k0, uint32_t k1, uint32_t m)
{
  uint32_t a, b;
  tf2x32(k0, k1, 0u, m, a, b);
  return a ^ b;
}

__device__ __forceinline__ float jax_normal_from_bits(uint32_t bits)
{
  float f = __uint_as_float((bits >> 9) | 0x3f800000u) - 1.0f;
  const float lo = -0.99999994f;
  float u = fmaxf(lo, f * 2.0f + lo);
  float w = -log1pf(-u * u);
  float p;
  if (w < 5.0f) {
    w -= 2.5f;
    p =          2.81022636e-08f;
    p = fmaf(p, w, 3.43273939e-07f);
    p = fmaf(p, w, -3.5233877e-06f);
    p = fmaf(p, w, -4.39150654e-06f);
    p = fmaf(p, w, 0.00021858087f);
    p = fmaf(p, w, -0.00125372503f);
    p = fmaf(p, w, -0.00417768164f);
    p = fmaf(p, w, 0.246640727f);
    p = fmaf(p, w, 1.50140941f);
  } else {
    w = sqrtf(w) - 3.0f;
    p =          -0.000200214257f;
    p = fmaf(p, w, 0.000100950558f);
    p = fmaf(p, w, 0.00134934322f);
    p = fmaf(p, w, -0.00367342844f);
    p = fmaf(p, w, 0.00573950773f);
    p = fmaf(p, w, -0.0076224613f);
    p = fmaf(p, w, 0.00943887047f);
    p = fmaf(p, w, 1.00167406f);
    p = fmaf(p, w, 2.83297682f);
  }
  return 1.4142135623730951f * (p * u);
}

__device__ __forceinline__ float gelu(float v)
{
  return 0.5f * v * (1.0f + erff(v * 0.7071067811865475f));
}

// ---------------- init: x,y (in d_out), BN accumulators ----------------
__global__ void k_init(const float* __restrict__ y0, const float* __restrict__ x0,
                       float* __restrict__ x, float* __restrict__ y,
                       float* __restrict__ bn)
{
  int gid = blockIdx.x * blockDim.x + threadIdx.x;
  int stride = gridDim.x * blockDim.x;
  for (int i = gid; i < B * DX; i += stride) x[i] = x0[i % DX];
  for (int i = gid; i < B; i += stride) y[i] = y0[0];
  for (int i = gid; i < NSTEPS * 4 * H; i += stride) bn[i] = 0.0f;
}

// ---------------- prep: bf16 transposed weights ----------------
__global__ void k_prep(const float* __restrict__ W1, const float* __restrict__ W2,
                       const float* __restrict__ W3, const float* __restrict__ W4,
                       ushort* __restrict__ w1t, ushort* __restrict__ w2t,
                       ushort* __restrict__ w3t, ushort* __restrict__ w4t)
{
  int gid = blockIdx.x * blockDim.x + threadIdx.x;
  int stride = gridDim.x * blockDim.x;
  for (int i = gid; i < H * KIN; i += stride) {
    int c = i >> 7, k = i & (KIN - 1);
    w1t[i] = f2bf(k < 101 ? W1[k * H + c] : 0.0f);
  }
  for (int i = gid; i < H * H; i += stride) {
    int c = i >> 9, k = i & (H - 1);
    w2t[i] = f2bf(W2[k * H + c]);
    w3t[i] = f2bf(W3[k * H + c]);
  }
  for (int i = gid; i < N4 * H; i += stride) {
    int c = i >> 9, k = i & (H - 1);
    w4t[i] = f2bf(c < DD ? W4[k * DD + c] : 0.0f);
  }
}

// ---------------- A: h1=gelu([x,t]@W1+b1); g=gelu(h1@W2+b2) bf16; BN1 stats
// grid 512: mb = bid>>1 (16 rows), nb = bid&1 (256-col half of layer-2 output)
__global__ __launch_bounds__(256, 2) void k_l12(
    const float* __restrict__ x, const ushort* __restrict__ w1t, const float* __restrict__ b1,
    const ushort* __restrict__ w2t, const float* __restrict__ b2, float tval,
    ushort* __restrict__ g, float* __restrict__ bns, float* __restrict__ bnq)
{
  __shared__ ushort xt[16][136];   // 128 + 8 pad (16B granule) -> conflict-free b128
  __shared__ ushort h1[16][520];   // 512 + 8 pad
  const int tid = threadIdx.x;
  const int mb = blockIdx.x >> 1;
  const int nb = blockIdx.x & 1;
  const int base = mb * 16;

  for (int idx = tid; idx < 16 * KIN; idx += 256) {
    int r = idx >> 7, k = idx & (KIN - 1);
    float v = (k < DX) ? x[(base + r) * DX + k] : (k == DX ? tval : 0.0f);
    xt[r][k] = f2bf(v);
  }
  __syncthreads();

  const int w = tid >> 6, lane = tid & 63;
  const int lr = lane & 15, lg = lane >> 4;

  // GEMM1: wave computes h1 cols [w*128, w*128+128)
  {
    f32x4 acc[8];
#pragma unroll
    for (int t = 0; t < 8; t++) acc[t] = (f32x4)(0.0f);
#pragma unroll
    for (int ks = 0; ks < 4; ks++) {
      bf8 a = *(const bf8*)&xt[lr][ks * 32 + lg * 8];
#pragma unroll
      for (int t = 0; t < 8; t++) {
        int col = w * 128 + t * 16 + lr;
        bf8 b = *(const bf8*)(w1t + col * KIN + ks * 32 + lg * 8);
        acc[t] = mfma16(a, b, acc[t]);
      }
    }
#pragma unroll
    for (int t = 0; t < 8; t++) {
      int col = w * 128 + t * 16 + lr;
      float bb = b1[col];
#pragma unroll
      for (int r = 0; r < 4; r++)
        h1[lg * 4 + r][col] = f2bf(gelu(acc[t][r] + bb));
    }
  }
  __syncthreads();

  // GEMM2: out cols [nb*256 + w*64, +64)
  {
    f32x4 acc[4];
#pragma unroll
    for (int t = 0; t < 4; t++) acc[t] = (f32x4)(0.0f);
#pragma unroll
    for (int ks = 0; ks < 16; ks++) {
      bf8 a = *(const bf8*)&h1[lr][ks * 32 + lg * 8];
#pragma unroll
      for (int t = 0; t < 4; t++) {
        int col = nb * 256 + w * 64 + t * 16 + lr;
        bf8 b = *(const bf8*)(w2t + col * H + ks * 32 + lg * 8);
        acc[t] = mfma16(a, b, acc[t]);
      }
    }
#pragma unroll
    for (int t = 0; t < 4; t++) {
      int col = nb * 256 + w * 64 + t * 16 + lr;
      float bb = b2[col];
      float s = 0.0f, q = 0.0f;
#pragma unroll
      for (int r = 0; r < 4; r++) {
        float v = gelu(acc[t][r] + bb);
        g[(base + lg * 4 + r) * H + col] = f2bf(v);
        s += v; q += v * v;
      }
      s += __shfl_xor(s, 16); s += __shfl_xor(s, 32);
      q += __shfl_xor(q, 16); q += __shfl_xor(q, 32);
      if (lane < 16) { unsafeAtomicAdd(&bns[col], s); unsafeAtomicAdd(&bnq[col], q); }
    }
  }
}

// ---------------- B: n2=BN1(g); g=gelu(n2@W3+b3) in place; BN2 stats
// grid 256 (no n-split -> in-place g is race-free: block reads its rows, syncs, rewrites)
__global__ __launch_bounds__(256, 2) void k_bn3(
    ushort* __restrict__ g,
    const float* __restrict__ bns, const float* __restrict__ bnq,
    const float* __restrict__ gamma, const float* __restrict__ beta,
    const ushort* __restrict__ wt, const float* __restrict__ bvec,
    float* __restrict__ obns, float* __restrict__ obnq)
{
  __shared__ float sc[H], sh[H];
  __shared__ ushort at[16][520];
  const int tid = threadIdx.x;
  const int base = blockIdx.x * 16;

  for (int c = tid; c < H; c += 256) {
    float m = bns[c] * (1.0f / B);
    float v = bnq[c] * (1.0f / B) - m * m;
    float s = gamma[c] * rsqrtf(v + 1e-5f);
    sc[c] = s; sh[c] = beta[c] - m * s;
  }
  __syncthreads();
  for (int idx = tid; idx < 16 * H / 4; idx += 256) {
    int r = idx >> 7, k4 = (idx & 127) * 4;
    ushort4 gv = *(const ushort4*)&g[(base + r) * H + k4];
    ushort4 o;
    o.x = f2bf(fmaf(bf2f(gv.x), sc[k4 + 0], sh[k4 + 0]));
    o.y = f2bf(fmaf(bf2f(gv.y), sc[k4 + 1], sh[k4 + 1]));
    o.z = f2bf(fmaf(bf2f(gv.z), sc[k4 + 2], sh[k4 + 2]));
    o.w = f2bf(fmaf(bf2f(gv.w), sc[k4 + 3], sh[k4 + 3]));
    *(ushort4*)&at[r][k4] = o;
  }
  __syncthreads();

  const int w = tid >> 6, lane = tid & 63;
  const int lr = lane & 15, lg = lane >> 4;
  f32x4 acc[8];
#pragma unroll
  for (int t = 0; t < 8; t++) acc[t] = (f32x4)(0.0f);
#pragma unroll
  for (int ks = 0; ks < 16; ks++) {
    bf8 a = *(const bf8*)&at[lr][ks * 32 + lg * 8];
#pragma unroll
    for (int t = 0; t < 8; t++) {
      int col = w * 128 + t * 16 + lr;
      bf8 b = *(const bf8*)(wt + col * H + ks * 32 + lg * 8);
      acc[t] = mfma16(a, b, acc[t]);
    }
  }
#pragma unroll
  for (int t = 0; t < 8; t++) {
    int col = w * 128 + t * 16 + lr;
    float bb = bvec[col];
    float s = 0.0f, q = 0.0f;
#pragma unroll
    for (int r = 0; r < 4; r++) {
      float v = gelu(acc[t][r] + bb);
      g[(base + lg * 4 + r) * H + col] = f2bf(v);
      s += v; q += v * v;
    }
    s += __shfl_xor(s, 16); s += __shfl_xor(s, 32);
    q += __shfl_xor(q, 16); q += __shfl_xor(q, 32);
    if (lane < 16) { unsafeAtomicAdd(&obns[col], s); unsafeAtomicAdd(&obnq[col], q); }
  }
}

// ---------------- C: n3=BN2(g); z=n3@W4+b4; RNG; update x,y. grid 256
__global__ __launch_bounds__(256, 2) void k_bn4(
    const ushort* __restrict__ g,
    const float* __restrict__ bns, const float* __restrict__ bnq,
    const float* __restrict__ gamma, const float* __restrict__ beta,
    const ushort* __restrict__ w4t, const float* __restrict__ b4,
    int step, float* __restrict__ x, float* __restrict__ y)
{
  __shared__ float sc[H], sh[H];
  __shared__ ushort at[16][520];
  __shared__ float ys1[4][16], ys2[4][16];
  const int tid = threadIdx.x;
  const int base = blockIdx.x * 16;

  for (int c = tid; c < H; c += 256) {
    float m = bns[c] * (1.0f / B);
    float v = bnq[c] * (1.0f / B) - m * m;
    float s = gamma[c] * rsqrtf(v + 1e-5f);
    sc[c] = s; sh[c] = beta[c] - m * s;
  }
  __syncthreads();
  for (int idx = tid; idx < 16 * H / 4; idx += 256) {
    int r = idx >> 7, k4 = (idx & 127) * 4;
    ushort4 gv = *(const ushort4*)&g[(base + r) * H + k4];
    ushort4 o;
    o.x = f2bf(fmaf(bf2f(gv.x), sc[k4 + 0], sh[k4 + 0]));
    o.y = f2bf(fmaf(bf2f(gv.y), sc[k4 + 1], sh[k4 + 1]));
    o.z = f2bf(fmaf(bf2f(gv.z), sc[k4 + 2], sh[k4 + 2]));
    o.w = f2bf(fmaf(bf2f(gv.w), sc[k4 + 3], sh[k4 + 3]));
    *(ushort4*)&at[r][k4] = o;
  }
  __syncthreads();

  const int w = tid >> 6, lane = tid & 63;
  const int lr = lane & 15, lg = lane >> 4;
  f32x4 acc[2];
  acc[0] = (f32x4)(0.0f); acc[1] = (f32x4)(0.0f);
#pragma unroll
  for (int ks = 0; ks < 16; ks++) {
    bf8 a = *(const bf8*)&at[lr][ks * 32 + lg * 8];
#pragma unroll
    for (int t = 0; t < 2; t++) {
      int col = (w * 2 + t) * 16 + lr;
      bf8 b = *(const bf8*)(w4t + col * H + ks * 32 + lg * 8);
      acc[t] = mfma16(a, b, acc[t]);
    }
  }

  uint32_t k0, k1;
  step_keys(step, k0, k1);
  float zz[4] = {0, 0, 0, 0}, zw[4] = {0, 0, 0, 0};
#pragma unroll
  for (int t = 0; t < 2; t++) {
    int col = (w * 2 + t) * 16 + lr;
    if (col < DD) {
      float bb = b4[col];
#pragma unroll
      for (int r = 0; r < 4; r++) {
        int grow = base + lg * 4 + r;
        float z = acc[t][r] + bb;
        uint32_t m = (uint32_t)grow * (uint32_t)DD + (uint32_t)col;
        float dW = 0.125f * jax_normal_from_bits(jax_bits(k0, k1, m));
        x[grow * DX + col] += 1.4142135623730951f * dW;
        zz[r] += z * z;
        zw[r] += z * dW;
      }
    }
  }
#pragma unroll
  for (int r = 0; r < 4; r++) {
    zz[r] += __shfl_xor(zz[r], 1); zz[r] += __shfl_xor(zz[r], 2);
    zz[r] += __shfl_xor(zz[r], 4); zz[r] += __shfl_xor(zz[r], 8);
    zw[r] += __shfl_xor(zw[r], 1); zw[r] += __shfl_xor(zw[r], 2);
    zw[r] += __shfl_xor(zw[r], 4); zw[r] += __shfl_xor(zw[r], 8);
  }
  if ((lane & 15) == 0) {
#pragma unroll
    for (int r = 0; r < 4; r++) {
      ys1[w][lg * 4 + r] = zz[r];
      ys2[w][lg * 4 + r] = zw[r];
    }
  }
  __syncthreads();
  if (tid < 16) {
    float s1 = ys1[0][tid] + ys1[1][tid] + ys1[2][tid] + ys1[3][tid];
    float s2 = ys2[0][tid] + ys2[1][tid] + ys2[2][tid] + ys2[3][tid];
    y[base + tid] += 0.5f * (1.0f / NSTEPS) * s1 + s2;
  }
}

extern "C" void kernel_launch(void* const* d_in, const int* in_sizes, int n_in,
                              void* d_out, int out_size, void* d_ws, size_t ws_size,
                              hipStream_t stream)
{
  const float* y0  = (const float*)d_in[0];
  const float* W1  = (const float*)d_in[1];
  const float* b1  = (const float*)d_in[2];
  const float* W2  = (const float*)d_in[3];
  const float* b2  = (const float*)d_in[4];
  const float* W3  = (const float*)d_in[5];
  const float* b3  = (const float*)d_in[6];
  const float* W4  = (const float*)d_in[7];
  const float* b4  = (const float*)d_in[8];
  const float* ga1 = (const float*)d_in[9];
  const float* be1 = (const float*)d_in[10];
  const float* ga2 = (const float*)d_in[11];
  const float* be2 = (const float*)d_in[12];
  const float* x0  = (const float*)d_in[13];

  float* x = (float*)d_out;        // B*DX
  float* y = x + B * DX;           // B

  float* bn = (float*)d_ws;                      // NSTEPS*4*H floats (512 KB)
  ushort* ub  = (ushort*)(bn + NSTEPS * 4 * H);
  ushort* g   = ub;                              // B*H bf16 (4 MB)
  ushort* w1t = g + B * H;                       // H*KIN
  ushort* w2t = w1t + H * KIN;                   // H*H
  ushort* w3t = w2t + H * H;                     // H*H
  ushort* w4t = w3t + H * H;                     // N4*H
  // total ws: 0.5 MB + 4 MB + ~1.3 MB = ~5.8 MB

  k_init<<<512, 256, 0, stream>>>(y0, x0, x, y, bn);
  k_prep<<<512, 256, 0, stream>>>(W1, W2, W3, W4, w1t, w2t, w3t, w4t);

  const float dt = 1.0f / NSTEPS;
  for (int s = 0; s < NSTEPS; ++s) {
    float* bn1s = bn + s * 4 * H;
    float* bn1q = bn1s + H;
    float* bn2s = bn1s + 2 * H;
    float* bn2q = bn1s + 3 * H;
    k_l12<<<512, 256, 0, stream>>>(x, w1t, b1, w2t, b2, (float)s * dt, g, bn1s, bn1q);
    k_bn3<<<256, 256, 0, stream>>>(g, bn1s, bn1q, ga1, be1, w3t, b3, bn2s, bn2q);
    k_bn4<<<256, 256, 0, stream>>>(g, bn2s, bn2q, ga2, be2, w4t, b4, s, x, y);
  }
}

// Round 5
// 4911.505 us; speedup vs baseline: 2.2064x; 1.0392x over previous
//
#include <hip/hip_runtime.h>
#include <stdint.h>

#define B 4096
#define DX 100
#define H 512
#define DD 100
#define NSTEPS 64
#define KIN 128      // padded input K for layer 1 (101 -> 128)
#define N4 128       // padded N for layer 4 (100 -> 128, keeps masked-wave loads in-bounds)

typedef short bf8 __attribute__((ext_vector_type(8)));    // 8 x bf16 (4 VGPR)
typedef float f32x4 __attribute__((ext_vector_type(4)));  // MFMA C/D

__device__ __forceinline__ ushort f2bf(float f) {
  uint32_t u = __float_as_uint(f);
  u += 0x7fffu + ((u >> 16) & 1u);   // RNE
  return (ushort)(u >> 16);
}
__device__ __forceinline__ float bf2f(ushort h) {
  return __uint_as_float((uint32_t)h << 16);
}
__device__ __forceinline__ f32x4 mfma16(bf8 a, bf8 b, f32x4 c) {
  return __builtin_amdgcn_mfma_f32_16x16x32_bf16(a, b, c, 0, 0, 0);
}

// ---------------- JAX threefry2x32 (20 rounds) ----------------
__device__ __forceinline__ void tf2x32(uint32_t k0, uint32_t k1,
                                       uint32_t x0, uint32_t x1,
                                       uint32_t& o0, uint32_t& o1)
{
  uint32_t ks2 = 0x1BD11BDAu ^ k0 ^ k1;
  x0 += k0; x1 += k1;
#define RND(r) { x0 += x1; x1 = (x1 << (r)) | (x1 >> (32 - (r))); x1 ^= x0; }
  RND(13) RND(15) RND(26) RND(6)   x0 += k1;  x1 += ks2 + 1u;
  RND(17) RND(29) RND(16) RND(24)  x0 += ks2; x1 += k0  + 2u;
  RND(13) RND(15) RND(26) RND(6)   x0 += k0;  x1 += k1  + 3u;
  RND(17) RND(29) RND(16) RND(24)  x0 += k1;  x1 += ks2 + 4u;
  RND(13) RND(15) RND(26) RND(6)   x0 += ks2; x1 += k0  + 5u;
#undef RND
  o0 = x0; o1 = x1;
}

// threefry_partitionable=True: split(key(42),64) -> key[s] = threefry((0,42),(0,s))
__device__ __forceinline__ void step_keys(int step, uint32_t& k0, uint32_t& k1)
{
  tf2x32(0u, 42u, 0u, (uint32_t)step, k0, k1);
}
// partitionable random_bits: counter (0,m), bits = o0 ^ o1
__device__ __forceinline__ uint32_t jax_bits(uint32_t k0, uint32_t k1, uint32_t m)
{
  uint32_t a, b;
  tf2x32(k0, k1, 0u, m, a, b);
  return a ^ b;
}

__device__ __forceinline__ float jax_normal_from_bits(uint32_t bits)
{
  float f = __uint_as_float((bits >> 9) | 0x3f800000u) - 1.0f;
  const float lo = -0.99999994f;
  float u = fmaxf(lo, f * 2.0f + lo);
  float w = -log1pf(-u * u);
  float p;
  if (w < 5.0f) {
    w -= 2.5f;
    p =          2.81022636e-08f;
    p = fmaf(p, w, 3.43273939e-07f);
    p = fmaf(p, w, -3.5233877e-06f);
    p = fmaf(p, w, -4.39150654e-06f);
    p = fmaf(p, w, 0.00021858087f);
    p = fmaf(p, w, -0.00125372503f);
    p = fmaf(p, w, -0.00417768164f);
    p = fmaf(p, w, 0.246640727f);
    p = fmaf(p, w, 1.50140941f);
  } else {
    w = sqrtf(w) - 3.0f;
    p =          -0.000200214257f;
    p = fmaf(p, w, 0.000100950558f);
    p = fmaf(p, w, 0.00134934322f);
    p = fmaf(p, w, -0.00367342844f);
    p = fmaf(p, w, 0.00573950773f);
    p = fmaf(p, w, -0.0076224613f);
    p = fmaf(p, w, 0.00943887047f);
    p = fmaf(p, w, 1.00167406f);
    p = fmaf(p, w, 2.83297682f);
  }
  return 1.4142135623730951f * (p * u);
}

__device__ __forceinline__ float gelu(float v)
{
  return 0.5f * v * (1.0f + erff(v * 0.7071067811865475f));
}

// ---------------- init: x,y (in d_out), BN accumulators ----------------
__global__ void k_init(const float* __restrict__ y0, const float* __restrict__ x0,
                       float* __restrict__ x, float* __restrict__ y,
                       float* __restrict__ bn)
{
  int gid = blockIdx.x * blockDim.x + threadIdx.x;
  int stride = gridDim.x * blockDim.x;
  for (int i = gid; i < B * DX; i += stride) x[i] = x0[i % DX];
  for (int i = gid; i < B; i += stride) y[i] = y0[0];
  for (int i = gid; i < NSTEPS * 4 * H; i += stride) bn[i] = 0.0f;
}

// ---------------- prep: bf16 transposed weights ----------------
__global__ void k_prep(const float* __restrict__ W1, const float* __restrict__ W2,
                       const float* __restrict__ W3, const float* __restrict__ W4,
                       ushort* __restrict__ w1t, ushort* __restrict__ w2t,
                       ushort* __restrict__ w3t, ushort* __restrict__ w4t)
{
  int gid = blockIdx.x * blockDim.x + threadIdx.x;
  int stride = gridDim.x * blockDim.x;
  for (int i = gid; i < H * KIN; i += stride) {
    int c = i >> 7, k = i & (KIN - 1);
    w1t[i] = f2bf(k < 101 ? W1[k * H + c] : 0.0f);
  }
  for (int i = gid; i < H * H; i += stride) {
    int c = i >> 9, k = i & (H - 1);
    w2t[i] = f2bf(W2[k * H + c]);
    w3t[i] = f2bf(W3[k * H + c]);
  }
  for (int i = gid; i < N4 * H; i += stride) {
    int c = i >> 9, k = i & (H - 1);
    w4t[i] = f2bf(c < DD ? W4[k * DD + c] : 0.0f);
  }
}

// ---------------- A: h1=gelu([x,t]@W1+b1); g1=gelu(h1@W2+b2) bf16; BN1 stats
// grid 1024: mb = bid>>2 (16 rows), nb = bid&3 (128-col slice of layer-2 output)
__global__ __launch_bounds__(256, 4) void k_l12(
    const float* __restrict__ x, const ushort* __restrict__ w1t, const float* __restrict__ b1,
    const ushort* __restrict__ w2t, const float* __restrict__ b2, float tval,
    ushort* __restrict__ g1, float* __restrict__ bns, float* __restrict__ bnq)
{
  __shared__ ushort xt[16][136];   // 128 + 8 pad
  __shared__ ushort h1[16][520];   // 512 + 8 pad
  const int tid = threadIdx.x;
  const int mb = blockIdx.x >> 2;
  const int nb = blockIdx.x & 3;
  const int base = mb * 16;

  for (int idx = tid; idx < 16 * KIN; idx += 256) {
    int r = idx >> 7, k = idx & (KIN - 1);
    float v = (k < DX) ? x[(base + r) * DX + k] : (k == DX ? tval : 0.0f);
    xt[r][k] = f2bf(v);
  }
  __syncthreads();

  const int w = tid >> 6, lane = tid & 63;
  const int lr = lane & 15, lg = lane >> 4;

  // GEMM1: wave computes h1 cols [w*128, +128)  (full h1 needed as GEMM2 K-input)
  {
    f32x4 acc[8];
#pragma unroll
    for (int t = 0; t < 8; t++) acc[t] = (f32x4)(0.0f);
#pragma unroll
    for (int ks = 0; ks < 4; ks++) {
      bf8 a = *(const bf8*)&xt[lr][ks * 32 + lg * 8];
#pragma unroll
      for (int t = 0; t < 8; t++) {
        int col = w * 128 + t * 16 + lr;
        bf8 b = *(const bf8*)(w1t + col * KIN + ks * 32 + lg * 8);
        acc[t] = mfma16(a, b, acc[t]);
      }
    }
#pragma unroll
    for (int t = 0; t < 8; t++) {
      int col = w * 128 + t * 16 + lr;
      float bb = b1[col];
#pragma unroll
      for (int r = 0; r < 4; r++)
        h1[lg * 4 + r][col] = f2bf(gelu(acc[t][r] + bb));
    }
  }
  __syncthreads();

  // GEMM2: block covers out cols [nb*128, +128); wave w: 2 sub-tiles of 16
  {
    f32x4 acc[2];
    acc[0] = (f32x4)(0.0f); acc[1] = (f32x4)(0.0f);
#pragma unroll
    for (int ks = 0; ks < 16; ks++) {
      bf8 a = *(const bf8*)&h1[lr][ks * 32 + lg * 8];
#pragma unroll
      for (int t = 0; t < 2; t++) {
        int col = nb * 128 + w * 32 + t * 16 + lr;
        bf8 b = *(const bf8*)(w2t + col * H + ks * 32 + lg * 8);
        acc[t] = mfma16(a, b, acc[t]);
      }
    }
#pragma unroll
    for (int t = 0; t < 2; t++) {
      int col = nb * 128 + w * 32 + t * 16 + lr;
      float bb = b2[col];
      float s = 0.0f, q = 0.0f;
#pragma unroll
      for (int r = 0; r < 4; r++) {
        float v = gelu(acc[t][r] + bb);
        g1[(base + lg * 4 + r) * H + col] = f2bf(v);
        s += v; q += v * v;
      }
      s += __shfl_xor(s, 16); s += __shfl_xor(s, 32);
      q += __shfl_xor(q, 16); q += __shfl_xor(q, 32);
      if (lane < 16) { unsafeAtomicAdd(&bns[col], s); unsafeAtomicAdd(&bnq[col], q); }
    }
  }
}

// ---------------- B: n2=BN1(g1); g2=gelu(n2@W3+b3); BN2 stats
// grid 1024: mb = bid>>2, nb = bid&3
__global__ __launch_bounds__(256, 4) void k_bn3(
    const ushort* __restrict__ g1, ushort* __restrict__ g2,
    const float* __restrict__ bns, const float* __restrict__ bnq,
    const float* __restrict__ gamma, const float* __restrict__ beta,
    const ushort* __restrict__ wt, const float* __restrict__ bvec,
    float* __restrict__ obns, float* __restrict__ obnq)
{
  __shared__ float sc[H], sh[H];
  __shared__ ushort at[16][520];
  const int tid = threadIdx.x;
  const int mb = blockIdx.x >> 2;
  const int nb = blockIdx.x & 3;
  const int base = mb * 16;

  for (int c = tid; c < H; c += 256) {
    float m = bns[c] * (1.0f / B);
    float v = bnq[c] * (1.0f / B) - m * m;
    float s = gamma[c] * rsqrtf(v + 1e-5f);
    sc[c] = s; sh[c] = beta[c] - m * s;
  }
  __syncthreads();
  for (int idx = tid; idx < 16 * H / 4; idx += 256) {
    int r = idx >> 7, k4 = (idx & 127) * 4;
    ushort4 gv = *(const ushort4*)&g1[(base + r) * H + k4];
    ushort4 o;
    o.x = f2bf(fmaf(bf2f(gv.x), sc[k4 + 0], sh[k4 + 0]));
    o.y = f2bf(fmaf(bf2f(gv.y), sc[k4 + 1], sh[k4 + 1]));
    o.z = f2bf(fmaf(bf2f(gv.z), sc[k4 + 2], sh[k4 + 2]));
    o.w = f2bf(fmaf(bf2f(gv.w), sc[k4 + 3], sh[k4 + 3]));
    *(ushort4*)&at[r][k4] = o;
  }
  __syncthreads();

  const int w = tid >> 6, lane = tid & 63;
  const int lr = lane & 15, lg = lane >> 4;
  f32x4 acc[2];
  acc[0] = (f32x4)(0.0f); acc[1] = (f32x4)(0.0f);
#pragma unroll
  for (int ks = 0; ks < 16; ks++) {
    bf8 a = *(const bf8*)&at[lr][ks * 32 + lg * 8];
#pragma unroll
    for (int t = 0; t < 2; t++) {
      int col = nb * 128 + w * 32 + t * 16 + lr;
      bf8 b = *(const bf8*)(wt + col * H + ks * 32 + lg * 8);
      acc[t] = mfma16(a, b, acc[t]);
    }
  }
#pragma unroll
  for (int t = 0; t < 2; t++) {
    int col = nb * 128 + w * 32 + t * 16 + lr;
    float bb = bvec[col];
    float s = 0.0f, q = 0.0f;
#pragma unroll
    for (int r = 0; r < 4; r++) {
      float v = gelu(acc[t][r] + bb);
      g2[(base + lg * 4 + r) * H + col] = f2bf(v);
      s += v; q += v * v;
    }
    s += __shfl_xor(s, 16); s += __shfl_xor(s, 32);
    q += __shfl_xor(q, 16); q += __shfl_xor(q, 32);
    if (lane < 16) { unsafeAtomicAdd(&obns[col], s); unsafeAtomicAdd(&obnq[col], q); }
  }
}

// ---------------- C: n3=BN2(g2); z=n3@W4+b4; RNG; update x,y
// grid 512: mb = bid>>1, nb = bid&1 (64-col slice); y via atomics
__global__ __launch_bounds__(256, 4) void k_bn4(
    const ushort* __restrict__ g2,
    const float* __restrict__ bns, const float* __restrict__ bnq,
    const float* __restrict__ gamma, const float* __restrict__ beta,
    const ushort* __restrict__ w4t, const float* __restrict__ b4,
    int step, float* __restrict__ x, float* __restrict__ y)
{
  __shared__ float sc[H], sh[H];
  __shared__ ushort at[16][520];
  __shared__ float ys1[4][16], ys2[4][16];
  const int tid = threadIdx.x;
  const int mb = blockIdx.x >> 1;
  const int nb = blockIdx.x & 1;
  const int base = mb * 16;

  for (int c = tid; c < H; c += 256) {
    float m = bns[c] * (1.0f / B);
    float v = bnq[c] * (1.0f / B) - m * m;
    float s = gamma[c] * rsqrtf(v + 1e-5f);
    sc[c] = s; sh[c] = beta[c] - m * s;
  }
  __syncthreads();
  for (int idx = tid; idx < 16 * H / 4; idx += 256) {
    int r = idx >> 7, k4 = (idx & 127) * 4;
    ushort4 gv = *(const ushort4*)&g2[(base + r) * H + k4];
    ushort4 o;
    o.x = f2bf(fmaf(bf2f(gv.x), sc[k4 + 0], sh[k4 + 0]));
    o.y = f2bf(fmaf(bf2f(gv.y), sc[k4 + 1], sh[k4 + 1]));
    o.z = f2bf(fmaf(bf2f(gv.z), sc[k4 + 2], sh[k4 + 2]));
    o.w = f2bf(fmaf(bf2f(gv.w), sc[k4 + 3], sh[k4 + 3]));
    *(ushort4*)&at[r][k4] = o;
  }
  __syncthreads();

  const int w = tid >> 6, lane = tid & 63;
  const int lr = lane & 15, lg = lane >> 4;
  const int col = nb * 64 + w * 16 + lr;     // < N4=128, in-bounds (zero-padded)
  f32x4 acc = (f32x4)(0.0f);
#pragma unroll
  for (int ks = 0; ks < 16; ks++) {
    bf8 a = *(const bf8*)&at[lr][ks * 32 + lg * 8];
    bf8 b = *(const bf8*)(w4t + col * H + ks * 32 + lg * 8);
    acc = mfma16(a, b, acc);
  }

  uint32_t k0, k1;
  step_keys(step, k0, k1);
  float zz[4] = {0, 0, 0, 0}, zw[4] = {0, 0, 0, 0};
  if (col < DD) {
    float bb = b4[col];
#pragma unroll
    for (int r = 0; r < 4; r++) {
      int grow = base + lg * 4 + r;
      float z = acc[r] + bb;
      uint32_t m = (uint32_t)grow * (uint32_t)DD + (uint32_t)col;
      float dW = 0.125f * jax_normal_from_bits(jax_bits(k0, k1, m));
      x[grow * DX + col] += 1.4142135623730951f * dW;
      zz[r] = z * z;
      zw[r] = z * dW;
    }
  }
#pragma unroll
  for (int r = 0; r < 4; r++) {
    zz[r] += __shfl_xor(zz[r], 1); zz[r] += __shfl_xor(zz[r], 2);
    zz[r] += __shfl_xor(zz[r], 4); zz[r] += __shfl_xor(zz[r], 8);
    zw[r] += __shfl_xor(zw[r], 1); zw[r] += __shfl_xor(zw[r], 2);
    zw[r] += __shfl_xor(zw[r], 4); zw[r] += __shfl_xor(zw[r], 8);
  }
  if ((lane & 15) == 0) {
#pragma unroll
    for (int r = 0; r < 4; r++) {
      ys1[w][lg * 4 + r] = zz[r];
      ys2[w][lg * 4 + r] = zw[r];
    }
  }
  __syncthreads();
  if (tid < 16) {
    float s1 = ys1[0][tid] + ys1[1][tid] + ys1[2][tid] + ys1[3][tid];
    float s2 = ys2[0][tid] + ys2[1][tid] + ys2[2][tid] + ys2[3][tid];
    unsafeAtomicAdd(&y[base + tid], 0.5f * (1.0f / NSTEPS) * s1 + s2);
  }
}

extern "C" void kernel_launch(void* const* d_in, const int* in_sizes, int n_in,
                              void* d_out, int out_size, void* d_ws, size_t ws_size,
                              hipStream_t stream)
{
  const float* y0  = (const float*)d_in[0];
  const float* W1  = (const float*)d_in[1];
  const float* b1  = (const float*)d_in[2];
  const float* W2  = (const float*)d_in[3];
  const float* b2  = (const float*)d_in[4];
  const float* W3  = (const float*)d_in[5];
  const float* b3  = (const float*)d_in[6];
  const float* W4  = (const float*)d_in[7];
  const float* b4  = (const float*)d_in[8];
  const float* ga1 = (const float*)d_in[9];
  const float* be1 = (const float*)d_in[10];
  const float* ga2 = (const float*)d_in[11];
  const float* be2 = (const float*)d_in[12];
  const float* x0  = (const float*)d_in[13];

  float* x = (float*)d_out;        // B*DX
  float* y = x + B * DX;           // B

  float* bn = (float*)d_ws;                      // NSTEPS*4*H floats (512 KB)
  ushort* ub  = (ushort*)(bn + NSTEPS * 4 * H);
  ushort* g1  = ub;                              // B*H bf16 (4 MB)
  ushort* g2  = g1 + B * H;                      // B*H bf16 (4 MB)
  ushort* w1t = g2 + B * H;                      // H*KIN
  ushort* w2t = w1t + H * KIN;                   // H*H
  ushort* w3t = w2t + H * H;                     // H*H
  ushort* w4t = w3t + H * H;                     // N4*H
  // total ws ~ 9.9 MB

  k_init<<<512, 256, 0, stream>>>(y0, x0, x, y, bn);
  k_prep<<<512, 256, 0, stream>>>(W1, W2, W3, W4, w1t, w2t, w3t, w4t);

  const float dt = 1.0f / NSTEPS;
  for (int s = 0; s < NSTEPS; ++s) {
    float* bn1s = bn + s * 4 * H;
    float* bn1q = bn1s + H;
    float* bn2s = bn1s + 2 * H;
    float* bn2q = bn1s + 3 * H;
    k_l12<<<1024, 256, 0, stream>>>(x, w1t, b1, w2t, b2, (float)s * dt, g1, bn1s, bn1q);
    k_bn3<<<1024, 256, 0, stream>>>(g1, g2, bn1s, bn1q, ga1, be1, w3t, b3, bn2s, bn2q);
    k_bn4<<<512, 256, 0, stream>>>(g2, bn2s, bn2q, ga2, be2, w4t, b4, s, x, y);
  }
}

// Round 6
// 2845.512 us; speedup vs baseline: 3.8084x; 1.7261x over previous
//
#include <hip/hip_runtime.h>
#include <stdint.h>

#define B 4096
#define DX 100
#define H 512
#define DD 100
#define NSTEPS 64
#define KIN 128      // padded K for layer 1 (101 -> 128)
#define N4 128       // padded N for layer 4 (100 -> 128)

typedef short bf8 __attribute__((ext_vector_type(8)));    // 8 x bf16
typedef float f32x4 __attribute__((ext_vector_type(4)));  // MFMA C/D

__device__ __forceinline__ ushort f2bf(float f) {
  uint32_t u = __float_as_uint(f);
  u += 0x7fffu + ((u >> 16) & 1u);   // RNE
  return (ushort)(u >> 16);
}
__device__ __forceinline__ float bf2f(ushort h) {
  return __uint_as_float((uint32_t)h << 16);
}
__device__ __forceinline__ f32x4 mfma16(bf8 a, bf8 b, f32x4 c) {
  return __builtin_amdgcn_mfma_f32_16x16x32_bf16(a, b, c, 0, 0, 0);
}

// ---------------- JAX threefry2x32 (20 rounds) ----------------
__device__ __forceinline__ void tf2x32(uint32_t k0, uint32_t k1,
                                       uint32_t x0, uint32_t x1,
                                       uint32_t& o0, uint32_t& o1)
{
  uint32_t ks2 = 0x1BD11BDAu ^ k0 ^ k1;
  x0 += k0; x1 += k1;
#define RND(r) { x0 += x1; x1 = (x1 << (r)) | (x1 >> (32 - (r))); x1 ^= x0; }
  RND(13) RND(15) RND(26) RND(6)   x0 += k1;  x1 += ks2 + 1u;
  RND(17) RND(29) RND(16) RND(24)  x0 += ks2; x1 += k0  + 2u;
  RND(13) RND(15) RND(26) RND(6)   x0 += k0;  x1 += k1  + 3u;
  RND(17) RND(29) RND(16) RND(24)  x0 += k1;  x1 += ks2 + 4u;
  RND(13) RND(15) RND(26) RND(6)   x0 += ks2; x1 += k0  + 5u;
#undef RND
  o0 = x0; o1 = x1;
}
// threefry_partitionable=True: split(key(42),64) -> key[s] = threefry((0,42),(0,s))
__device__ __forceinline__ void step_keys(int step, uint32_t& k0, uint32_t& k1)
{
  tf2x32(0u, 42u, 0u, (uint32_t)step, k0, k1);
}
// partitionable random_bits: counter (0,m), bits = o0 ^ o1
__device__ __forceinline__ uint32_t jax_bits(uint32_t k0, uint32_t k1, uint32_t m)
{
  uint32_t a, b;
  tf2x32(k0, k1, 0u, m, a, b);
  return a ^ b;
}

__device__ __forceinline__ float jax_normal_from_bits(uint32_t bits)
{
  float f = __uint_as_float((bits >> 9) | 0x3f800000u) - 1.0f;
  const float lo = -0.99999994f;
  float u = fmaxf(lo, f * 2.0f + lo);
  float w = -log1pf(-u * u);
  float p;
  if (w < 5.0f) {
    w -= 2.5f;
    p =          2.81022636e-08f;
    p = fmaf(p, w, 3.43273939e-07f);
    p = fmaf(p, w, -3.5233877e-06f);
    p = fmaf(p, w, -4.39150654e-06f);
    p = fmaf(p, w, 0.00021858087f);
    p = fmaf(p, w, -0.00125372503f);
    p = fmaf(p, w, -0.00417768164f);
    p = fmaf(p, w, 0.246640727f);
    p = fmaf(p, w, 1.50140941f);
  } else {
    w = sqrtf(w) - 3.0f;
    p =          -0.000200214257f;
    p = fmaf(p, w, 0.000100950558f);
    p = fmaf(p, w, 0.00134934322f);
    p = fmaf(p, w, -0.00367342844f);
    p = fmaf(p, w, 0.00573950773f);
    p = fmaf(p, w, -0.0076224613f);
    p = fmaf(p, w, 0.00943887047f);
    p = fmaf(p, w, 1.00167406f);
    p = fmaf(p, w, 2.83297682f);
  }
  return 1.4142135623730951f * (p * u);
}

__device__ __forceinline__ float gelu(float v)
{
  return 0.5f * v * (1.0f + erff(v * 0.7071067811865475f));
}

// ---------------- init: x,y (in d_out), BN accumulators ----------------
__global__ void k_init(const float* __restrict__ y0, const float* __restrict__ x0,
                       float* __restrict__ x, float* __restrict__ y,
                       float* __restrict__ bn)
{
  int gid = blockIdx.x * blockDim.x + threadIdx.x;
  int stride = gridDim.x * blockDim.x;
  for (int i = gid; i < B * DX; i += stride) x[i] = x0[i % DX];
  for (int i = gid; i < B; i += stride) y[i] = y0[0];
  for (int i = gid; i < NSTEPS * 4 * H; i += stride) bn[i] = 0.0f;
}

// ---------------- prep: bf16 transposed weights ----------------
__global__ void k_prep(const float* __restrict__ W1, const float* __restrict__ W2,
                       const float* __restrict__ W3, const float* __restrict__ W4,
                       ushort* __restrict__ w1t, ushort* __restrict__ w2t,
                       ushort* __restrict__ w3t, ushort* __restrict__ w4t)
{
  int gid = blockIdx.x * blockDim.x + threadIdx.x;
  int stride = gridDim.x * blockDim.x;
  for (int i = gid; i < H * KIN; i += stride) {
    int c = i >> 7, k = i & (KIN - 1);
    w1t[i] = f2bf(k < 101 ? W1[k * H + c] : 0.0f);
  }
  for (int i = gid; i < H * H; i += stride) {
    int c = i >> 9, k = i & (H - 1);
    w2t[i] = f2bf(W2[k * H + c]);
    w3t[i] = f2bf(W3[k * H + c]);
  }
  for (int i = gid; i < N4 * H; i += stride) {
    int c = i >> 9, k = i & (H - 1);
    w4t[i] = f2bf(c < DD ? W4[k * DD + c] : 0.0f);
  }
}

// ---------------- prologue: h1 = gelu([x,t]@W1+b1) for step 0
// grid 512: mb = bid>>3 (64 rows), nb = bid&7 (64-col slice)
__global__ __launch_bounds__(256, 4) void k_l1(
    const float* __restrict__ x, const ushort* __restrict__ w1t,
    const float* __restrict__ b1, ushort* __restrict__ h1g, float tval)
{
  __shared__ ushort xt[64][136];
  const int tid = threadIdx.x;
  const int mb = blockIdx.x >> 3, nb = blockIdx.x & 7;
  const int base = mb * 64;

  for (int i = tid; i < 64 * KIN; i += 256) {
    int r = i >> 7, k = i & (KIN - 1);
    float v = (k < DX) ? x[(base + r) * DX + k] : (k == DX ? tval : 0.0f);
    xt[r][k] = f2bf(v);
  }
  __syncthreads();

  const int w = tid >> 6, lane = tid & 63, lr = lane & 15, lg = lane >> 4;
  const int col = nb * 64 + w * 16 + lr;
  f32x4 acc[4];
#pragma unroll
  for (int mi = 0; mi < 4; mi++) acc[mi] = (f32x4)(0.0f);
#pragma unroll
  for (int ks = 0; ks < 4; ks++) {
    bf8 b = *(const bf8*)(w1t + col * KIN + ks * 32 + lg * 8);
#pragma unroll
    for (int mi = 0; mi < 4; mi++) {
      bf8 a = *(const bf8*)&xt[mi * 16 + lr][ks * 32 + lg * 8];
      acc[mi] = mfma16(a, b, acc[mi]);
    }
  }
  float bb = b1[col];
#pragma unroll
  for (int mi = 0; mi < 4; mi++)
#pragma unroll
    for (int r = 0; r < 4; r++)
      h1g[(base + mi * 16 + lg * 4 + r) * H + col] = f2bf(gelu(acc[mi][r] + bb));
}

// ---------------- kA: g1 = gelu(h1@W2+b2); BN1 stats
// grid 512: mb = bid>>3 (64 rows), nb = bid&7 (64-col slice). B-reuse 4.
__global__ __launch_bounds__(256, 4) void k_l2(
    const ushort* __restrict__ h1g, const ushort* __restrict__ w2t,
    const float* __restrict__ b2, ushort* __restrict__ g1,
    float* __restrict__ bns, float* __restrict__ bnq)
{
  __shared__ ushort at[64][264];   // K-chunk 256 + 8 pad
  const int tid = threadIdx.x;
  const int mb = blockIdx.x >> 3, nb = blockIdx.x & 7;
  const int base = mb * 64;
  const int w = tid >> 6, lane = tid & 63, lr = lane & 15, lg = lane >> 4;
  const int col = nb * 64 + w * 16 + lr;

  f32x4 acc[4];
#pragma unroll
  for (int mi = 0; mi < 4; mi++) acc[mi] = (f32x4)(0.0f);

#pragma unroll
  for (int c = 0; c < 2; c++) {
    if (c) __syncthreads();
    for (int i = tid; i < 2048; i += 256) {         // 64 rows x 32 vec8
      int r = i >> 5, kk = (i & 31) * 8;
      *(bf8*)&at[r][kk] = *(const bf8*)&h1g[(base + r) * H + c * 256 + kk];
    }
    __syncthreads();
#pragma unroll
    for (int ks = 0; ks < 8; ks++) {
      bf8 b = *(const bf8*)(w2t + col * H + c * 256 + ks * 32 + lg * 8);
#pragma unroll
      for (int mi = 0; mi < 4; mi++) {
        bf8 a = *(const bf8*)&at[mi * 16 + lr][ks * 32 + lg * 8];
        acc[mi] = mfma16(a, b, acc[mi]);
      }
    }
  }

  float bb = b2[col], s = 0.0f, q = 0.0f;
#pragma unroll
  for (int mi = 0; mi < 4; mi++)
#pragma unroll
    for (int r = 0; r < 4; r++) {
      float v = gelu(acc[mi][r] + bb);
      g1[(base + mi * 16 + lg * 4 + r) * H + col] = f2bf(v);
      s += v; q += v * v;
    }
  s += __shfl_xor(s, 16); s += __shfl_xor(s, 32);
  q += __shfl_xor(q, 16); q += __shfl_xor(q, 32);
  if (lane < 16) { unsafeAtomicAdd(&bns[col], s); unsafeAtomicAdd(&bnq[col], q); }
}

// ---------------- kB: n2 = BN1(g1); g2 = gelu(n2@W3+b3); BN2 stats
// grid 512, same tiling as kA
__global__ __launch_bounds__(256, 4) void k_bn_l3(
    const ushort* __restrict__ g1, ushort* __restrict__ g2,
    const float* __restrict__ bns, const float* __restrict__ bnq,
    const float* __restrict__ gamma, const float* __restrict__ beta,
    const ushort* __restrict__ w3t, const float* __restrict__ b3,
    float* __restrict__ obns, float* __restrict__ obnq)
{
  __shared__ float sc[H], sh[H];
  __shared__ ushort at[64][264];
  const int tid = threadIdx.x;
  const int mb = blockIdx.x >> 3, nb = blockIdx.x & 7;
  const int base = mb * 64;
  const int w = tid >> 6, lane = tid & 63, lr = lane & 15, lg = lane >> 4;
  const int col = nb * 64 + w * 16 + lr;

  for (int c = tid; c < H; c += 256) {
    float m = bns[c] * (1.0f / B);
    float v = bnq[c] * (1.0f / B) - m * m;
    float s = gamma[c] * rsqrtf(v + 1e-5f);
    sc[c] = s; sh[c] = beta[c] - m * s;
  }

  f32x4 acc[4];
#pragma unroll
  for (int mi = 0; mi < 4; mi++) acc[mi] = (f32x4)(0.0f);

#pragma unroll
  for (int c = 0; c < 2; c++) {
    __syncthreads();   // c=0: sc/sh ready; c=1: protect LDS rewrite
    for (int i = tid; i < 64 * 64; i += 256) {      // 64 rows x 64 vec4
      int r = i >> 6, k4 = (i & 63) * 4, gk = c * 256 + k4;
      ushort4 gv = *(const ushort4*)&g1[(base + r) * H + gk];
      ushort4 o;
      o.x = f2bf(fmaf(bf2f(gv.x), sc[gk + 0], sh[gk + 0]));
      o.y = f2bf(fmaf(bf2f(gv.y), sc[gk + 1], sh[gk + 1]));
      o.z = f2bf(fmaf(bf2f(gv.z), sc[gk + 2], sh[gk + 2]));
      o.w = f2bf(fmaf(bf2f(gv.w), sc[gk + 3], sh[gk + 3]));
      *(ushort4*)&at[r][k4] = o;
    }
    __syncthreads();
#pragma unroll
    for (int ks = 0; ks < 8; ks++) {
      bf8 b = *(const bf8*)(w3t + col * H + c * 256 + ks * 32 + lg * 8);
#pragma unroll
      for (int mi = 0; mi < 4; mi++) {
        bf8 a = *(const bf8*)&at[mi * 16 + lr][ks * 32 + lg * 8];
        acc[mi] = mfma16(a, b, acc[mi]);
      }
    }
  }

  float bb = b3[col], s = 0.0f, q = 0.0f;
#pragma unroll
  for (int mi = 0; mi < 4; mi++)
#pragma unroll
    for (int r = 0; r < 4; r++) {
      float v = gelu(acc[mi][r] + bb);
      g2[(base + mi * 16 + lg * 4 + r) * H + col] = f2bf(v);
      s += v; q += v * v;
    }
  s += __shfl_xor(s, 16); s += __shfl_xor(s, 32);
  q += __shfl_xor(q, 16); q += __shfl_xor(q, 32);
  if (lane < 16) { unsafeAtomicAdd(&obns[col], s); unsafeAtomicAdd(&obnq[col], q); }
}

// ---------------- kC: n3=BN2(g2); z=n3@W4+b4; RNG; x,y update; l1 for next step
// grid 256, 512 threads (8 waves). Rows block-local -> y plain store, xt stays in LDS.
// g2 and h1g alias the same buffer: block reads its 16 g2 rows early, rewrites them
// as next-step h1 late (same block, barrier between) -- race-free.
__global__ __launch_bounds__(512, 4) void k_c(
    const ushort* __restrict__ g2,
    const float* __restrict__ bns, const float* __restrict__ bnq,
    const float* __restrict__ gamma, const float* __restrict__ beta,
    const ushort* __restrict__ w4t, const float* __restrict__ b4,
    const ushort* __restrict__ w1t, const float* __restrict__ b1,
    int step, float tnext, int do_l1,
    float* __restrict__ x, float* __restrict__ y, ushort* __restrict__ h1g)
{
  __shared__ float sc[H], sh[H];
  __shared__ ushort at[16][520];
  __shared__ ushort xt[16][136];
  __shared__ float ys1[8][16], ys2[8][16];
  const int tid = threadIdx.x;
  const int base = blockIdx.x * 16;

  for (int c = tid; c < H; c += 512) {
    float m = bns[c] * (1.0f / B);
    float v = bnq[c] * (1.0f / B) - m * m;
    float s = gamma[c] * rsqrtf(v + 1e-5f);
    sc[c] = s; sh[c] = beta[c] - m * s;
  }
  __syncthreads();
  for (int i = tid; i < 16 * 128; i += 512) {
    int r = i >> 7, k4 = (i & 127) * 4;
    ushort4 gv = *(const ushort4*)&g2[(base + r) * H + k4];
    ushort4 o;
    o.x = f2bf(fmaf(bf2f(gv.x), sc[k4 + 0], sh[k4 + 0]));
    o.y = f2bf(fmaf(bf2f(gv.y), sc[k4 + 1], sh[k4 + 1]));
    o.z = f2bf(fmaf(bf2f(gv.z), sc[k4 + 2], sh[k4 + 2]));
    o.w = f2bf(fmaf(bf2f(gv.w), sc[k4 + 3], sh[k4 + 3]));
    *(ushort4*)&at[r][k4] = o;
  }
  __syncthreads();

  const int w = tid >> 6, lane = tid & 63, lr = lane & 15, lg = lane >> 4;
  const int col = w * 16 + lr;     // 0..127, matches padded w4t
  f32x4 acc = (f32x4)(0.0f);
#pragma unroll
  for (int ks = 0; ks < 16; ks++) {
    bf8 a = *(const bf8*)&at[lr][ks * 32 + lg * 8];
    bf8 b = *(const bf8*)(w4t + col * H + ks * 32 + lg * 8);
    acc = mfma16(a, b, acc);
  }

  uint32_t k0, k1;
  step_keys(step, k0, k1);
  float zz[4] = {0, 0, 0, 0}, zw[4] = {0, 0, 0, 0};
  if (col < DD) {
    float bb = b4[col];
#pragma unroll
    for (int r = 0; r < 4; r++) {
      int row = lg * 4 + r, grow = base + row;
      float z = acc[r] + bb;
      uint32_t m = (uint32_t)grow * (uint32_t)DD + (uint32_t)col;
      float dW = 0.125f * jax_normal_from_bits(jax_bits(k0, k1, m));
      float xn = x[grow * DX + col] + 1.4142135623730951f * dW;
      x[grow * DX + col] = xn;
      xt[row][col] = f2bf(xn);
      zz[r] = z * z;
      zw[r] = z * dW;
    }
  } else {
#pragma unroll
    for (int r = 0; r < 4; r++)
      xt[lg * 4 + r][col] = (col == DX) ? f2bf(tnext) : (ushort)0;
  }
#pragma unroll
  for (int r = 0; r < 4; r++) {
    zz[r] += __shfl_xor(zz[r], 1); zz[r] += __shfl_xor(zz[r], 2);
    zz[r] += __shfl_xor(zz[r], 4); zz[r] += __shfl_xor(zz[r], 8);
    zw[r] += __shfl_xor(zw[r], 1); zw[r] += __shfl_xor(zw[r], 2);
    zw[r] += __shfl_xor(zw[r], 4); zw[r] += __shfl_xor(zw[r], 8);
  }
  if (lr == 0) {
#pragma unroll
    for (int r = 0; r < 4; r++) {
      ys1[w][lg * 4 + r] = zz[r];
      ys2[w][lg * 4 + r] = zw[r];
    }
  }
  __syncthreads();   // covers ys and xt writes
  if (tid < 16) {
    float s1 = 0.0f, s2 = 0.0f;
#pragma unroll
    for (int i = 0; i < 8; i++) { s1 += ys1[i][tid]; s2 += ys2[i][tid]; }
    y[base + tid] += 0.5f * (1.0f / NSTEPS) * s1 + s2;
  }

  if (do_l1) {
    // layer 1 for next step: xt(16x128) @ w1t -> h1 (16 x 512), 64 cols per wave
    f32x4 a1[4];
#pragma unroll
    for (int t = 0; t < 4; t++) a1[t] = (f32x4)(0.0f);
#pragma unroll
    for (int ks = 0; ks < 4; ks++) {
      bf8 a = *(const bf8*)&xt[lr][ks * 32 + lg * 8];
#pragma unroll
      for (int t = 0; t < 4; t++) {
        int cc = w * 64 + t * 16 + lr;
        bf8 b = *(const bf8*)(w1t + cc * KIN + ks * 32 + lg * 8);
        a1[t] = mfma16(a, b, a1[t]);
      }
    }
#pragma unroll
    for (int t = 0; t < 4; t++) {
      int cc = w * 64 + t * 16 + lr;
      float bb = b1[cc];
#pragma unroll
      for (int r = 0; r < 4; r++)
        h1g[(base + lg * 4 + r) * H + cc] = f2bf(gelu(a1[t][r] + bb));
    }
  }
}

extern "C" void kernel_launch(void* const* d_in, const int* in_sizes, int n_in,
                              void* d_out, int out_size, void* d_ws, size_t ws_size,
                              hipStream_t stream)
{
  const float* y0  = (const float*)d_in[0];
  const float* W1  = (const float*)d_in[1];
  const float* b1  = (const float*)d_in[2];
  const float* W2  = (const float*)d_in[3];
  const float* b2  = (const float*)d_in[4];
  const float* W3  = (const float*)d_in[5];
  const float* b3  = (const float*)d_in[6];
  const float* W4  = (const float*)d_in[7];
  const float* b4  = (const float*)d_in[8];
  const float* ga1 = (const float*)d_in[9];
  const float* be1 = (const float*)d_in[10];
  const float* ga2 = (const float*)d_in[11];
  const float* be2 = (const float*)d_in[12];
  const float* x0  = (const float*)d_in[13];

  float* x = (float*)d_out;        // B*DX
  float* y = x + B * DX;           // B

  float* bn = (float*)d_ws;                      // NSTEPS*4*H floats (512 KB)
  ushort* ub  = (ushort*)(bn + NSTEPS * 4 * H);
  ushort* g1  = ub;                              // B*H bf16 (4 MB)
  ushort* g2h = g1 + B * H;                      // B*H bf16 (4 MB) -- g2 AND h1 (aliased)
  ushort* w1t = g2h + B * H;                     // H*KIN
  ushort* w2t = w1t + H * KIN;                   // H*H
  ushort* w3t = w2t + H * H;                     // H*H
  ushort* w4t = w3t + H * H;                     // N4*H
  // total ws ~ 9.8 MB

  k_init<<<512, 256, 0, stream>>>(y0, x0, x, y, bn);
  k_prep<<<512, 256, 0, stream>>>(W1, W2, W3, W4, w1t, w2t, w3t, w4t);
  k_l1<<<512, 256, 0, stream>>>(x, w1t, b1, g2h, 0.0f);   // h1 for step 0

  const float dt = 1.0f / NSTEPS;
  for (int s = 0; s < NSTEPS; ++s) {
    float* bn1s = bn + s * 4 * H;
    float* bn1q = bn1s + H;
    float* bn2s = bn1s + 2 * H;
    float* bn2q = bn1s + 3 * H;
    k_l2   <<<512, 256, 0, stream>>>(g2h, w2t, b2, g1, bn1s, bn1q);
    k_bn_l3<<<512, 256, 0, stream>>>(g1, g2h, bn1s, bn1q, ga1, be1, w3t, b3, bn2s, bn2q);
    k_c    <<<256, 512, 0, stream>>>(g2h, bn2s, bn2q, ga2, be2, w4t, b4, w1t, b1,
                                     s, (float)(s + 1) * dt, (s < NSTEPS - 1) ? 1 : 0,
                                     x, y, g2h);
  }
}